// Round 8
// baseline (606.944 us; speedup 1.0000x reference)
//
#include <hip/hip_runtime.h>
#include <cstdint>
#include <cstddef>

typedef _Float16 f16;
typedef _Float16 f16x8 __attribute__((ext_vector_type(8)));
typedef float f32x4 __attribute__((ext_vector_type(4)));

// ---------------------------------------------------------------------------
// W is stored fragment-tiled for mfma_f32_16x16x32_f16's B operand:
// lane l of a wave holds B[n = nf*16 + (l&15)][k = kb*32 + (l>>4)*8 + j].
// Element (n,k) lives at flat f16 index
//   ((n>>4)*(K/32) + (k>>5))*512 + (((k>>3)&3)*16 + (n&15))*8 + (k&7)
// so a wave loads one fragment as ONE coalesced global_load_dwordx4.
// ---------------------------------------------------------------------------

// Wt tile for coef: k = i*8+g  ->  kb=i>>2, lane=(i&3)*16+(o&15), elem g
template <int I, int O>
__global__ void prep_coef(const float* __restrict__ coef,
                          const float* __restrict__ ssp,
                          f16* __restrict__ Wt) {
  constexpr int K32 = (9 * I) / 32;
  int tid = blockIdx.x * 256 + threadIdx.x;
  if (tid >= I * O) return;
  int i = tid / O, o = tid % O;             // o fastest -> coalesced coef reads
  float s = ssp[tid];
  const float* c = coef + (size_t)tid * 8;
  f16x8 out;
#pragma unroll
  for (int g = 0; g < 8; ++g) out[g] = (f16)(c[g] * s);
  size_t addr = ((size_t)(o >> 4) * K32 + (i >> 2)) * 512 +
                (size_t)(((i & 3) * 16) + (o & 15)) * 8;
  *(f16x8*)(Wt + addr) = out;
}

// Wt tile for base: k = 8I+i -> kb=I/4+(i>>5), lane=((i>>3)&3)*16+(o&15), elem i&7
template <int I, int O>
__global__ void prep_base(const float* __restrict__ sb, f16* __restrict__ Wt) {
  constexpr int K32 = (9 * I) / 32;
  int tid = blockIdx.x * 256 + threadIdx.x;
  if (tid >= (I / 8) * O) return;
  int i8 = tid / O, o = tid % O;            // o fastest -> coalesced writes
  f16x8 out;
#pragma unroll
  for (int s = 0; s < 8; ++s)
    out[s] = (f16)sb[(size_t)(i8 * 8 + s) * O + o];
  size_t addr = ((size_t)(o >> 4) * K32 + (I / 4) + (i8 >> 2)) * 512 +
                (size_t)(((i8 & 3) * 16) + (o & 15)) * 8;
  *(f16x8*)(Wt + addr) = out;
}

// ---------------------------------------------------------------------------
// 8-slot cubic B-spline basis, packed-shift form (verified R6, absmax 0.0625).
// ---------------------------------------------------------------------------
__device__ __forceinline__ f16x8 spline8(float h) {
  float v = __builtin_fmaf(2.5f, h, 5.5f);
  float c = floorf(v);
  float f = v - c;
  float f2 = f * f, f3 = f2 * f;
  float b3 = f3 * (1.f / 6.f);
  float t = 1.f - f;
  float b0 = t * t * t * (1.f / 6.f);
  float b1 = (2.f / 3.f) - f2 + 0.5f * f3;
  float b2 = 1.f - b0 - b1 - b3;
  unsigned int u01 =
      __builtin_bit_cast(unsigned int, __builtin_amdgcn_cvt_pkrtz(b0, b1));
  unsigned int u23 =
      __builtin_bit_cast(unsigned int, __builtin_amdgcn_cvt_pkrtz(b2, b3));
  unsigned long long pk = (unsigned long long)u01 |
                          ((unsigned long long)u23 << 32);
  int ci = (int)c;
  int s = (ci - 3) * 16;                // bit offset of slot c-3
  __uint128_t r = 0;
  if (s >= 0) {
    if (s < 128) r = (__uint128_t)pk << s;
  } else {
    int q = -s;
    if (q < 64) r = (__uint128_t)(pk >> q);
  }
  return __builtin_bit_cast(f16x8, r);
}

// ---------------------------------------------------------------------------
// Fused KAN GEMM, 128(M) x 256(N) tile, BK=64. R14: WAVE-PRIVATE A-TILES,
// ZERO BARRIERS.
//
// R7-R13 post-mortems: MfmaUtil pinned 28-32% across six schedules; per
// SIMD per step MFMA pipe 2483 cyc + VALU ~2800 of 7067 wall, neither pipe
// saturated. Shared cause: the 2 co-resident blocks run identical code
// launched together -> phase-locked (MFMA bursts collide, gen phases
// collide), and the per-step block barrier convoys all 4 waves on the
// slowest. Observed MfmaUtil == committed-work ratio (35%) == the aligned-
// phase prediction.
//
// R14: each wave generates the 64x64 A-subtile only IT consumes into a
// PRIVATE 8 KB LDS slice (dbuf: 2x4x64x64 f16 = 64 KB/block, 128 KB/CU,
// still 2 blocks/CU). Waves sharing rows duplicate gen (2x VALU: ~580
// cyc/wave/step, under the 1242-cyc MFMA shadow). ALL barriers removed --
// same-wave LDS RAW is ordered by the in-order per-wave DS pipe. Waves
// self-pace and drift into anti-phase; setprio now has real role diversity.
// Unlike R12 (register A-gen, uncoalesced H + spills), H loads keep R11's
// coalesced shape (8 rows x 32B per instruction) and av reads keep the
// proven conflict-free swizzle. Gen layout: r=lane>>3, j=lane&7, rows
// q*8+r (q=0..7), js = j^r constant per lane.
//
// Kept: XCD pinning (8 (x,z) pairs == wgid%8 == XCD, W slice 2.36 MB/XCD
// L2-resident; strided split-K), B register pipeline (bvB at step head
// under MFMA half0; next bvA under MFMA half1), setprio on MFMA clusters,
// atomicAdd split-K epilogue. Arithmetic bit-identical (absmax 0.0625).
// ---------------------------------------------------------------------------
template <int I, int ATOMIC, int NX, int NZ>
__global__ __launch_bounds__(256, 2) void gemm_kan(const float* __restrict__ H,
                                                   const f16* __restrict__ W,
                                                   float* __restrict__ C,
                                                   int N) {
  constexpr int K = 9 * I;
  constexpr int KB = 8 * I;                   // spline/base boundary (mult 64)
  constexpr int K32 = K / 32;
  constexpr int KSTEP = 64 * NZ;              // strided split-K step
  constexpr int NSTEP = K / KSTEP;
  constexpr int BUF = 4 * 64 * 64;            // one buffer: 4 waves x 64x64
  __shared__ __align__(16) f16 sA[2 * BUF];   // 64 KB, wave-private slices
  const int t = threadIdx.x;
  const int wg = blockIdx.x;
  const int pr = wg & 7;                      // XCD-pair id (wgid%8 == XCD)
  const int n0 = (pr % NX) * 256;
  const int m0 = (wg >> 3) * 128;
  const int kBeg = (pr / NX) * 64;
  const int w = t >> 6, lane = t & 63;
  const int wm = (w >> 1) * 64, wn = (w & 1) * 128;
  const int lr = lane & 15, lq = lane >> 4;
  const int r_ = lane >> 3;                   // gen: row-in-octet 0..7
  const int j_ = lane & 7;                    // gen: i-offset / col chunk
  const int js = j_ ^ r_;                     // swizzled chunk (row&7 == r_)

  f16* myA = sA + w * (64 * 64);              // this wave's slice (per buf)

  f32x4 acc[4][8] = {};
  // gen row base: global row m0 + wm + r_ (+ q*8 per octet)
  const float* Hg = H + (size_t)(m0 + wm + r_) * I;

  float hs[8];

  // Generate MY 64x64 A-subtile for k-range [kg, kg+64) into private wb.
  auto genTile = [&](int kg, f16* wb) {
    if (kg < KB) {
#pragma unroll
      for (int q = 0; q < 8; ++q)
        *(f16x8*)&wb[(q * 8 + r_) * 64 + js * 8] = spline8(hs[q]);
      const int kn = kg + KSTEP;
      if (kn < KB) {
        const int i0n = kn >> 3;
#pragma unroll
        for (int q = 0; q < 8; ++q)
          hs[q] = Hg[(size_t)(q * 8) * I + i0n + j_];
      }
    } else {
      const int c0 = (kg - KB) + j_ * 8;      // 8 consecutive silu inputs
#pragma unroll
      for (int q = 0; q < 8; ++q) {
        const f32x4* p = (const f32x4*)(Hg + (size_t)(q * 8) * I + c0);
        f32x4 a0 = p[0], a1 = p[1];
        f16x8 o;
#pragma unroll
        for (int e = 0; e < 8; ++e) {
          float h = (e < 4) ? a0[e & 3] : a1[e & 3];
          o[e] = (f16)(h / (1.f + __expf(-h)));
        }
        *(f16x8*)&wb[(q * 8 + r_) * 64 + js * 8] = o;
      }
    }
  };

  // prologue: H prefetch, first B half, generate tile 0 (no barrier: private)
  {
    const int i0 = kBeg >> 3;                 // kBeg <= 192 < KB always
#pragma unroll
    for (int q = 0; q < 8; ++q)
      hs[q] = Hg[(size_t)(q * 8) * I + i0 + j_];
  }
  const f16* pk = W + ((size_t)((n0 + wn) >> 4) * K32 + (kBeg >> 5)) * 512 +
                  lane * 8;
  f16x8 bvA[8];
#pragma unroll
  for (int j = 0; j < 8; ++j)
    bvA[j] = *(const f16x8*)(pk + (size_t)j * K32 * 512);
  genTile(kBeg, myA);                         // also prefetches hs for next

  int cur = 0;
  for (int s = 0; s < NSTEP; ++s) {
    const f16* rb = myA + cur * BUF;
    f16* wb = myA + (cur ^ 1) * BUF;

    // B frags for kk=32 of THIS step: latency hides under av0 + MFMA half0.
    f16x8 bvB[8];
#pragma unroll
    for (int j = 0; j < 8; ++j)
      bvB[j] = *(const f16x8*)(pk + (size_t)j * K32 * 512 + 512);

    // av half 0 from private LDS (row = i*16+lr local, chunk lq swizzled)
    f16x8 av[4];
#pragma unroll
    for (int i = 0; i < 4; ++i) {
      const int ra = i * 16 + lr;
      const int ca = lq ^ (ra & 7);
      av[i] = *(const f16x8*)&rb[ra * 64 + ca * 8];
    }

    __builtin_amdgcn_s_setprio(1);
#pragma unroll
    for (int i = 0; i < 4; ++i)
#pragma unroll
      for (int j = 0; j < 8; ++j)
        acc[i][j] = __builtin_amdgcn_mfma_f32_16x16x32_f16(av[i], bvA[j],
                                                           acc[i][j], 0, 0, 0);
    __builtin_amdgcn_s_setprio(0);

    // av half 1
#pragma unroll
    for (int i = 0; i < 4; ++i) {
      const int ra = i * 16 + lr;
      const int ca = (4 + lq) ^ (ra & 7);
      av[i] = *(const f16x8*)&rb[ra * 64 + ca * 8];
    }

    // Generate NEXT tile into my other buffer (overlaps MFMA half1; DS ops
    // are in-order per wave, so next step's reads see these writes).
    const bool more = (s + 1 < NSTEP);
    if (more) genTile(kBeg + (s + 1) * KSTEP, wb);

    // NEXT step's bv(kk=0): free-flying, waited by counted vmcnt at use.
    pk += (size_t)(KSTEP / 32) * 512;
    if (more) {
#pragma unroll
      for (int j = 0; j < 8; ++j)
        bvA[j] = *(const f16x8*)(pk + (size_t)j * K32 * 512);
    }

    __builtin_amdgcn_s_setprio(1);
#pragma unroll
    for (int i = 0; i < 4; ++i)
#pragma unroll
      for (int j = 0; j < 8; ++j)
        acc[i][j] = __builtin_amdgcn_mfma_f32_16x16x32_f16(av[i], bvB[j],
                                                           acc[i][j], 0, 0, 0);
    __builtin_amdgcn_s_setprio(0);

    cur ^= 1;                                 // no barrier: tile is private
  }

#pragma unroll
  for (int i = 0; i < 4; ++i) {
#pragma unroll
    for (int j = 0; j < 8; ++j) {
      const int col = n0 + wn + j * 16 + lr;
#pragma unroll
      for (int r = 0; r < 4; ++r) {
        const int row = m0 + wm + i * 16 + lq * 4 + r;
        if (ATOMIC)
          atomicAdd(&C[(size_t)row * N + col], acc[i][j][r]);
        else
          C[(size_t)row * N + col] = acc[i][j][r];
      }
    }
  }
}

// ---------------------------------------------------------------------------
extern "C" void kernel_launch(void* const* d_in, const int* in_sizes, int n_in,
                              void* d_out, int out_size, void* d_ws,
                              size_t ws_size, hipStream_t stream) {
  const float* x     = (const float*)d_in[0];
  const float* coef1 = (const float*)d_in[1];
  const float* sb1   = (const float*)d_in[2];
  const float* ssp1  = (const float*)d_in[3];
  const float* coef2 = (const float*)d_in[4];
  const float* sb2   = (const float*)d_in[5];
  const float* ssp2  = (const float*)d_in[6];

  const int Mtot = 8192;
  const int I1 = 512, O1 = 2048, K1 = I1 * 9;   // 4608
  const int I2 = 2048, O2 = 512, K2 = I2 * 9;   // 18432

  char* ws = (char*)d_ws;
  const size_t szW1 = (size_t)O1 * K1 * sizeof(f16);     // 18.9 MB
  const size_t szW2 = (size_t)O2 * K2 * sizeof(f16);     // 18.9 MB
  const size_t szH  = (size_t)Mtot * O1 * sizeof(float); // 67.1 MB
  if (ws_size < szW1 + szW2 + szH) return;  // cannot run; fail visibly
  f16*   W1 = (f16*)ws;
  f16*   W2 = (f16*)(ws + szW1);
  float* h1 = (float*)(ws + szW1 + szW2);

  // weight prep (fragment-tiled layout, 16x16x32 B-operand tiles)
  {
    int n1 = I1 * O1;
    prep_coef<512, 2048><<<(n1 + 255) / 256, 256, 0, stream>>>(coef1, ssp1, W1);
    prep_base<512, 2048><<<(n1 / 8 + 255) / 256, 256, 0, stream>>>(sb1, W1);
    int n2 = I2 * O2;
    prep_coef<2048, 512><<<(n2 + 255) / 256, 256, 0, stream>>>(coef2, ssp2, W2);
    prep_base<2048, 512><<<(n2 / 8 + 255) / 256, 256, 0, stream>>>(sb2, W2);
  }

  // layer 1: h1 = KanAct(x) @ W1^T — 512 blocks, pair=(x), 2/CU.
  gemm_kan<512, 0, 8, 1><<<dim3(512), 256, 0, stream>>>(x, W1, h1, O1);

  // layer 2: out = KanAct(h1) @ W2^T — strided split-K=4, pair=(x,z).
  (void)hipMemsetAsync(d_out, 0, (size_t)Mtot * O2 * sizeof(float), stream);
  gemm_kan<2048, 1, 2, 4><<<dim3(512), 256, 0, stream>>>(h1, W2,
                                                         (float*)d_out, O2);
}